// Round 10
// baseline (209.381 us; speedup 1.0000x reference)
//
#include <hip/hip_runtime.h>
#include <hip/hip_bf16.h>

// MaskedDenseLayerMultiMasks: out[b,m,o] = sum_i x[b,m,i] * kernel[i,o] * masks[m,i,o]
// Round 10: ABLATION round (6 flat rounds => measure, don't theorize).
//   kernel A (mdl_mfma_kernel): r9 verbatim -> correct d_out, 52.4 µs baseline.
//   kernel B (mdl_ablate_loads): loads-only skeleton -- identical grid, LDS
//     footprint, barrier/waitcnt structure, X/Kn loads + mask DMA; NO LDS
//     staging writes, NO mask-LDS reads, NO convert, NO MFMA. REPS=4, tile
//     order rotated per rep (defeats CSE; asm keepalives with memory clobber
//     pin the loads, rule #17).
// Readout: T_loads = (bench_dur - 52.4us) / 4.
//   T_loads ~= 52us  -> memory-system-bound (L2/L3) -> next: traffic geometry
//   T_loads << 52us  -> on-chip-bound (LDS/VALU/barrier) -> next: lean staging

#define BATCH 512
#define NMASK 16
#define IN_D  1024
#define OUT_D 1024

#define BM 128
#define BN 128
#define BK 32
#define NT (IN_D / BK)   // 32
#define AKP 40           // A LDS k-stride (80B rows)
#define BKP 34           // B LDS k-stride (68B rows)
#define MFSZ (BK * BN)   // 4096 floats per mask tile
#define THREADS 512
#define ABREPS 4

using bf16x8 = __attribute__((ext_vector_type(8))) __bf16;
using bf16x4 = __attribute__((ext_vector_type(4))) __bf16;
using f32x4  = __attribute__((ext_vector_type(4))) float;
using f32x2  = __attribute__((ext_vector_type(2))) float;

typedef const __attribute__((address_space(1))) void gvoid_t;
typedef __attribute__((address_space(3))) void lvoid_t;

__device__ __forceinline__ void dma16(const void* g, const void* l) {
    __builtin_amdgcn_global_load_lds((gvoid_t*)(uintptr_t)g,
                                     (lvoid_t*)(uintptr_t)l, 16, 0, 0);
}

// ========================= kernel A: r9 verbatim =========================
__global__ void __launch_bounds__(THREADS, 4)
mdl_mfma_kernel(const float* __restrict__ X,   // (B, M, I)
                const float* __restrict__ Kn,  // (I, O)
                const float* __restrict__ Mk,  // (M, I, O)
                float* __restrict__ Out)       // (B, M, O)
{
    __shared__ __align__(16) float          Mf[3 * MFSZ];    // 48 KiB (ring)
    __shared__ __align__(16) unsigned short As[BM * AKP];    // 10 KiB
    __shared__ __align__(16) unsigned short Bs[BN * BKP];    // 8.5 KiB

    const int t = threadIdx.x;
    const int l = t & 63;
    const int w = t >> 6;          // wave 0..7

    const int raw = blockIdx.x;
    const int wg  = (raw & 7) * 64 + (raw >> 3);
    const int m   = wg >> 5;          // 0..15
    const int ob  = (wg >> 2) & 7;    // 0..7
    const int bb  = wg & 3;           // 0..3

    const int wr = w >> 2;            // 0..1
    const int wc = w & 3;             // 0..3

    f32x4 acc[4][2];
#pragma unroll
    for (int mi = 0; mi < 4; ++mi)
#pragma unroll
        for (int ni = 0; ni < 2; ++ni)
            acc[mi][ni] = (f32x4){0.f, 0.f, 0.f, 0.f};

    const int a_row = t >> 2;
    const int a_kh  = (t & 3) * 8;
    const int o2 = (t & 63) * 2;
    const int k4 = w * 4;

    const int obase = ob * BN;
    const float* Xa  = X + ((size_t)(bb * BM + a_row) * NMASK + m) * IN_D + a_kh;
    const float* Knb = Kn + obase + o2;
    const float* Mkm = Mk + (size_t)m * IN_D * OUT_D;

    auto DMA = [&](int tile, int c) {
        const int kt = tile * BK;
#pragma unroll
        for (int j = 0; j < 2; ++j) {
            const int k = j * 16 + w * 2 + (l >> 5);
            const float* gsrc = Mkm + (size_t)(kt + k) * OUT_D + obase + (l & 31) * 4;
            const float* ldst = &Mf[c * MFSZ + j * 2048 + w * 256];
            dma16(gsrc, ldst);
        }
    };

    auto MFMA_PHASE = [&]() {
        const int kg = (l >> 4) * 8;
        bf16x8 bfv[2];
#pragma unroll
        for (int ni = 0; ni < 2; ++ni) {
            const int n = wc * 32 + ni * 16 + (l & 15);
            bf16x4 lo = *(const bf16x4*)(&Bs[n * BKP + kg]);
            bf16x4 hi = *(const bf16x4*)(&Bs[n * BKP + kg + 4]);
            bf16x8 f;
            f[0] = lo[0]; f[1] = lo[1]; f[2] = lo[2]; f[3] = lo[3];
            f[4] = hi[0]; f[5] = hi[1]; f[6] = hi[2]; f[7] = hi[3];
            bfv[ni] = f;
        }
#pragma unroll
        for (int mi = 0; mi < 4; ++mi) {
            const int r = wr * 64 + mi * 16 + (l & 15);
            bf16x8 af = *(const bf16x8*)(&As[r * AKP + kg]);
#pragma unroll
            for (int ni = 0; ni < 2; ++ni)
                acc[mi][ni] = __builtin_amdgcn_mfma_f32_16x16x32_bf16(
                    af, bfv[ni], acc[mi][ni], 0, 0, 0);
        }
    };

    DMA(0, 0);
    DMA(1, 1);
    asm volatile("s_waitcnt vmcnt(2)" ::: "memory");
    __builtin_amdgcn_sched_barrier(0);
    __builtin_amdgcn_s_barrier();
    __builtin_amdgcn_sched_barrier(0);

    int c_cur = 0, c_nxt = 1, c_far = 2;

    for (int tt = 0; tt < NT; ++tt) {
        const int kt = tt * BK;

        f32x4 xv0 = *(const f32x4*)(Xa + kt);
        f32x4 xv1 = *(const f32x4*)(Xa + kt + 4);
        f32x2 kv[4];
#pragma unroll
        for (int r = 0; r < 4; ++r)
            kv[r] = *(const f32x2*)(Knb + (size_t)(kt + k4 + r) * OUT_D);
        __builtin_amdgcn_sched_barrier(0);

        const int tile_pf = (tt + 2 < NT) ? (tt + 2) : 0;
        DMA(tile_pf, c_far);
        __builtin_amdgcn_sched_barrier(0);

        {
            f32x2 mvv[4];
#pragma unroll
            for (int r = 0; r < 4; ++r)
                mvv[r] = *(const f32x2*)(&Mf[c_cur * MFSZ + (k4 + r) * BN + o2]);
#pragma unroll
            for (int c = 0; c < 2; ++c) {
                bf16x4 v;
#pragma unroll
                for (int r = 0; r < 4; ++r)
                    v[r] = (__bf16)(kv[r][c] * mvv[r][c]);
                *(bf16x4*)(&Bs[(o2 + c) * BKP + k4]) = v;
            }
            bf16x8 va;
#pragma unroll
            for (int j = 0; j < 4; ++j) {
                va[j]     = (__bf16)xv0[j];
                va[4 + j] = (__bf16)xv1[j];
            }
            *(bf16x8*)(&As[a_row * AKP + a_kh]) = va;
        }

        asm volatile("s_waitcnt lgkmcnt(0)" ::: "memory");
        __builtin_amdgcn_sched_barrier(0);
        __builtin_amdgcn_s_barrier();
        __builtin_amdgcn_sched_barrier(0);

        __builtin_amdgcn_s_setprio(1);
        MFMA_PHASE();
        __builtin_amdgcn_s_setprio(0);

        asm volatile("s_waitcnt vmcnt(2)" ::: "memory");
        __builtin_amdgcn_sched_barrier(0);
        __builtin_amdgcn_s_barrier();
        __builtin_amdgcn_sched_barrier(0);

        const int tmp = c_cur; c_cur = c_nxt; c_nxt = c_far; c_far = tmp;
    }

    asm volatile("s_waitcnt vmcnt(0)" ::: "memory");

    const int r0 = bb * BM + wr * 64 + (l >> 4) * 4;
    const int c0 = ob * BN + wc * 32 + (l & 15);
#pragma unroll
    for (int mi = 0; mi < 4; ++mi) {
#pragma unroll
        for (int j = 0; j < 4; ++j) {
            const size_t row = (size_t)(r0 + mi * 16 + j);
            float* op = Out + (row * NMASK + m) * OUT_D + c0;
#pragma unroll
            for (int ni = 0; ni < 2; ++ni)
                op[ni * 16] = acc[mi][ni][j];
        }
    }
}

// ================ kernel B: loads-only ablation (REPS=4) ================
__global__ void __launch_bounds__(THREADS, 4)
mdl_ablate_loads(const float* __restrict__ X,
                 const float* __restrict__ Kn,
                 const float* __restrict__ Mk)
{
    __shared__ __align__(16) float          Mf[3 * MFSZ];    // LDS footprint
    __shared__ __align__(16) unsigned short As[BM * AKP];    // parity with A
    __shared__ __align__(16) unsigned short Bs[BN * BKP];

    const int t = threadIdx.x;
    const int l = t & 63;
    const int w = t >> 6;

    const int raw = blockIdx.x;
    const int wg  = (raw & 7) * 64 + (raw >> 3);
    const int m   = wg >> 5;
    const int ob  = (wg >> 2) & 7;
    const int bb  = wg & 3;

    // keep As/Bs allocated (write-only shared stores are not elidable)
    if (t == 0) { As[0] = 1; Bs[0] = 1; }

    const int a_row = t >> 2;
    const int a_kh  = (t & 3) * 8;
    const int o2 = (t & 63) * 2;
    const int k4 = w * 4;

    const int obase = ob * BN;
    const float* Xa  = X + ((size_t)(bb * BM + a_row) * NMASK + m) * IN_D + a_kh;
    const float* Knb = Kn + obase + o2;
    const float* Mkm = Mk + (size_t)m * IN_D * OUT_D;

    auto DMA = [&](int tile, int c) {
        const int kt = tile * BK;
#pragma unroll
        for (int j = 0; j < 2; ++j) {
            const int k = j * 16 + w * 2 + (l >> 5);
            const float* gsrc = Mkm + (size_t)(kt + k) * OUT_D + obase + (l & 31) * 4;
            const float* ldst = &Mf[c * MFSZ + j * 2048 + w * 256];
            dma16(gsrc, ldst);
        }
    };

    DMA(0, 0);
    DMA(1, 1);
    asm volatile("s_waitcnt vmcnt(2)" ::: "memory");
    __builtin_amdgcn_sched_barrier(0);
    __builtin_amdgcn_s_barrier();
    __builtin_amdgcn_sched_barrier(0);

    int c_cur = 0, c_nxt = 1, c_far = 2;

    for (int rep = 0; rep < ABREPS; ++rep) {
        for (int tt = 0; tt < NT; ++tt) {
            // rotate tile order per rep: same footprint, different addresses
            const int tile = (tt + rep * 7) & (NT - 1);
            const int kt   = tile * BK;

            f32x4 xv0 = *(const f32x4*)(Xa + kt);
            f32x4 xv1 = *(const f32x4*)(Xa + kt + 4);
            f32x2 kv0 = *(const f32x2*)(Knb + (size_t)(kt + k4 + 0) * OUT_D);
            f32x2 kv1 = *(const f32x2*)(Knb + (size_t)(kt + k4 + 1) * OUT_D);
            f32x2 kv2 = *(const f32x2*)(Knb + (size_t)(kt + k4 + 2) * OUT_D);
            f32x2 kv3 = *(const f32x2*)(Knb + (size_t)(kt + k4 + 3) * OUT_D);
            __builtin_amdgcn_sched_barrier(0);

            DMA((tt + 2 + rep * 7) & (NT - 1), c_far);
            __builtin_amdgcn_sched_barrier(0);

            // consume loads exactly where staging would (same waitcnt/FIFO
            // retirement position); memory clobber defeats cross-rep CSE
            asm volatile("" :: "v"(xv0), "v"(xv1) : "memory");
            asm volatile("" :: "v"(kv0), "v"(kv1), "v"(kv2), "v"(kv3) : "memory");
            __builtin_amdgcn_sched_barrier(0);

            asm volatile("s_waitcnt lgkmcnt(0)" ::: "memory");
            __builtin_amdgcn_sched_barrier(0);
            __builtin_amdgcn_s_barrier();
            __builtin_amdgcn_sched_barrier(0);

            asm volatile("s_waitcnt vmcnt(2)" ::: "memory");
            __builtin_amdgcn_sched_barrier(0);
            __builtin_amdgcn_s_barrier();
            __builtin_amdgcn_sched_barrier(0);

            const int tmp = c_cur; c_cur = c_nxt; c_nxt = c_far; c_far = tmp;
        }
    }
    asm volatile("s_waitcnt vmcnt(0)" ::: "memory");
}

extern "C" void kernel_launch(void* const* d_in, const int* in_sizes, int n_in,
                              void* d_out, int out_size, void* d_ws, size_t ws_size,
                              hipStream_t stream) {
    (void)in_sizes; (void)n_in; (void)d_ws; (void)ws_size; (void)out_size;
    const float* X  = (const float*)d_in[0];
    const float* Kn = (const float*)d_in[1];
    const float* Mk = (const float*)d_in[2];
    float* Out = (float*)d_out;

    const int nblocks = (BATCH / BM) * (OUT_D / BN) * NMASK;  // 512
    mdl_mfma_kernel<<<nblocks, THREADS, 0, stream>>>(X, Kn, Mk, Out);
    mdl_ablate_loads<<<nblocks, THREADS, 0, stream>>>(X, Kn, Mk);
}

// Round 11
// 59.451 us; speedup vs baseline: 3.5219x; 3.5219x over previous
//
#include <hip/hip_runtime.h>
#include <hip/hip_bf16.h>

// MaskedDenseLayerMultiMasks: out[b,m,o] = sum_i x[b,m,i] * kernel[i,o] * masks[m,i,o]
// Round 11: 2-PASS. r10's ablation showed the load skeleton (X+Kn+mask merge
// inside the GEMM loop) is 78% of runtime. Pass 1 streams W = Kn*Mk -> bf16
// into d_ws in GEMM-ready k-major granule tiles (barrier-free, coalesced).
// Pass 2 is a lean GEMM: B-staging = 2 global_load_lds/thread/iter (zero VALU),
// BK=64 (16 iters), Bs ring-3 + counted vmcnt(2), conflict-free granule frags.

#define BATCH 512
#define NMASK 16
#define IN_D  1024
#define OUT_D 1024

#define BM 128
#define BN 128
#define BK 64
#define NT (IN_D / BK)        // 16
#define TILE_ELEMS (BN * BK)  // 8192 bf16 = 16 KiB per tile
#define THREADS 512

using bf16x8 = __attribute__((ext_vector_type(8))) __bf16;
using bf16x4 = __attribute__((ext_vector_type(4))) __bf16;
using f32x4  = __attribute__((ext_vector_type(4))) float;
using f32x2  = __attribute__((ext_vector_type(2))) float;
using u16x4  = __attribute__((ext_vector_type(4))) unsigned short;

typedef const __attribute__((address_space(1))) void gvoid_t;
typedef __attribute__((address_space(3))) void lvoid_t;

__device__ __forceinline__ void dma16(const void* g, const void* l) {
    __builtin_amdgcn_global_load_lds((gvoid_t*)(uintptr_t)g,
                                     (lvoid_t*)(uintptr_t)l, 16, 0, 0);
}

// =========== pass 1: W[m,i,o] = Kn[i,o]*Mk[m,i,o] -> bf16 tiled =============
// tile id = (m*8 + ob)*16 + k2. Tile = [8 k-octets][128 o] granules of 8 bf16:
// granule f = g*128 + o holds W[k = k2*64 + g*8 .. +8][o] (k-ascending).
// Thread t (wave w, lane l): columns o = {2l, 2l+1}, octet g = w.
// Writes 32B contiguous at tile*8192 + t*16 elems -> perfectly coalesced.
__global__ void __launch_bounds__(THREADS, 4)
mdl_prep_w(const float* __restrict__ Kn,
           const float* __restrict__ Mk,
           unsigned short* __restrict__ Wt)
{
    const int t = threadIdx.x;
    const int l = t & 63;
    const int w = t >> 6;

    const int raw = blockIdx.x;                    // 2048 blocks, 8 XCDs
    const int wg  = (raw & 7) * 256 + (raw >> 3);  // bijective
    const int m   = wg >> 7;
    const int ob  = (wg >> 4) & 7;
    const int k2  = wg & 15;

    const int i0 = k2 * 64 + w * 8;
    const int o0 = ob * BN + 2 * l;

    const float* mkb = Mk + ((size_t)m * IN_D + i0) * OUT_D + o0;
    const float* knb = Kn + (size_t)i0 * OUT_D + o0;

    f32x2 a[8], b[8];
#pragma unroll
    for (int r = 0; r < 8; ++r) {
        a[r] = *(const f32x2*)(mkb + (size_t)r * OUT_D);
        b[r] = *(const f32x2*)(knb + (size_t)r * OUT_D);
    }
    bf16x8 g0, g1;
#pragma unroll
    for (int r = 0; r < 8; ++r) {
        g0[r] = (__bf16)(a[r][0] * b[r][0]);   // column 2l,   k = i0+r
        g1[r] = (__bf16)(a[r][1] * b[r][1]);   // column 2l+1, k = i0+r
    }
    unsigned short* dst = Wt + (size_t)wg * TILE_ELEMS + t * 16;
    *(bf16x8*)(dst)     = g0;                  // granule f = 2t   = w*128 + 2l
    *(bf16x8*)(dst + 8) = g1;                  // granule f = 2t+1
}

// ======================= pass 2: lean MFMA GEMM =============================
__global__ void __launch_bounds__(THREADS, 4)
mdl_gemm(const float* __restrict__ X,
         const unsigned short* __restrict__ Wt,
         float* __restrict__ Out)
{
    __shared__ __align__(16) unsigned short As[2][TILE_ELEMS];  // 32 KiB
    __shared__ __align__(16) unsigned short Bs[3][TILE_ELEMS];  // 48 KiB

    const int t = threadIdx.x;
    const int l = t & 63;
    const int w = t >> 6;          // wave 0..7

    const int raw = blockIdx.x;    // 512 wgs, 8 XCDs, 64/XCD
    const int wg  = (raw & 7) * 64 + (raw >> 3);
    const int m   = wg >> 5;          // 0..15
    const int ob  = (wg >> 2) & 7;    // 0..7
    const int bb  = wg & 3;           // 0..3

    const int wr = w >> 2, wc = w & 3;   // wave -> 64x32 sub-tile

    f32x4 acc[4][2];
#pragma unroll
    for (int mi = 0; mi < 4; ++mi)
#pragma unroll
        for (int ni = 0; ni < 2; ++ni)
            acc[mi][ni] = (f32x4){0.f, 0.f, 0.f, 0.f};

    // A staging: 4 threads/row; thread covers k-octets {2(t&3), 2(t&3)+1}
    const int a_row = t >> 2;
    const int a_g0  = (t & 3) * 2;
    const float* Xa = X + ((size_t)(bb * BM + a_row) * NMASK + m) * IN_D + (t & 3) * 16;

    const unsigned short* Wb = Wt + (size_t)(m * 8 + ob) * NT * TILE_ELEMS;

    auto DMAB = [&](int tile, int c) {
#pragma unroll
        for (int j = 0; j < 2; ++j) {
            const unsigned short* src =
                Wb + (size_t)tile * TILE_ELEMS + (size_t)(j * 512 + w * 64 + l) * 8;
            dma16(src, &Bs[c][j * 4096 + w * 512]);   // + lane*16B by HW
        }
    };

    f32x4 xv0, xv1, xv2, xv3;   // X pipeline regs (named; loads fenced early)

    auto LOADX = [&](int kt) {
        xv0 = *(const f32x4*)(Xa + kt);
        xv1 = *(const f32x4*)(Xa + kt + 4);
        xv2 = *(const f32x4*)(Xa + kt + 8);
        xv3 = *(const f32x4*)(Xa + kt + 12);
    };
    auto STORE_A = [&](int buf) {
        bf16x8 v0, v1;
#pragma unroll
        for (int j = 0; j < 4; ++j) {
            v0[j] = (__bf16)xv0[j]; v0[4 + j] = (__bf16)xv1[j];
            v1[j] = (__bf16)xv2[j]; v1[4 + j] = (__bf16)xv3[j];
        }
        unsigned short* p = &As[buf][a_g0 * 1024 + a_row * 8];
        *(bf16x8*)p          = v0;
        *(bf16x8*)(p + 1024) = v1;
    };
    auto MFMAP = [&](int abuf, int bc) {
#pragma unroll
        for (int s = 0; s < 2; ++s) {
            const int gs = s * 4 + (l >> 4);
            bf16x8 bfv[2];
#pragma unroll
            for (int ni = 0; ni < 2; ++ni)
                bfv[ni] = *(const bf16x8*)
                    &Bs[bc][gs * 1024 + (wc * 32 + ni * 16 + (l & 15)) * 8];
#pragma unroll
            for (int mi = 0; mi < 4; ++mi) {
                bf16x8 af = *(const bf16x8*)
                    &As[abuf][gs * 1024 + (wr * 64 + mi * 16 + (l & 15)) * 8];
#pragma unroll
                for (int ni = 0; ni < 2; ++ni)
                    acc[mi][ni] = __builtin_amdgcn_mfma_f32_16x16x32_bf16(
                        af, bfv[ni], acc[mi][ni], 0, 0, 0);
            }
        }
    };

    // ---- prologue: X(0) + B-tiles 0,1 in flight; stage A(0) ----
    LOADX(0);
    __builtin_amdgcn_sched_barrier(0);
    DMAB(0, 0);
    DMAB(1, 1);
    __builtin_amdgcn_sched_barrier(0);
    STORE_A(0);                                    // dataflow-waits X only
    asm volatile("s_waitcnt lgkmcnt(0)" ::: "memory");
    __builtin_amdgcn_sched_barrier(0);
    asm volatile("s_waitcnt vmcnt(2)" ::: "memory");  // tile0 B landed
    __builtin_amdgcn_sched_barrier(0);
    __builtin_amdgcn_s_barrier();
    __builtin_amdgcn_sched_barrier(0);

    int c_cur = 0, c_nxt = 1, c_far = 2;

    for (int tt = 0; tt < NT; ++tt) {
        if (tt + 1 < NT) {
            LOADX((tt + 1) * BK);
            __builtin_amdgcn_sched_barrier(0);
        }
        DMAB((tt + 2 < NT) ? tt + 2 : 0, c_far);   // dummy near tail: uniform FIFO
        __builtin_amdgcn_sched_barrier(0);

        __builtin_amdgcn_s_setprio(1);
        MFMAP(tt & 1, c_cur);
        __builtin_amdgcn_s_setprio(0);

        if (tt + 1 < NT) STORE_A((tt + 1) & 1);    // X wait retires older DMAs too

        asm volatile("s_waitcnt lgkmcnt(0)" ::: "memory");
        __builtin_amdgcn_sched_barrier(0);
        asm volatile("s_waitcnt vmcnt(2)" ::: "memory");  // counted: 2 stay in flight
        __builtin_amdgcn_sched_barrier(0);
        __builtin_amdgcn_s_barrier();
        __builtin_amdgcn_sched_barrier(0);

        const int tmp = c_cur; c_cur = c_nxt; c_nxt = c_far; c_far = tmp;
    }
    asm volatile("s_waitcnt vmcnt(0)" ::: "memory");

    // ---- epilogue: C/D layout col = l&15, row = (l>>4)*4 + reg ----
    const int r0 = bb * BM + wr * 64 + (l >> 4) * 4;
    const int c0 = ob * BN + wc * 32 + (l & 15);
#pragma unroll
    for (int mi = 0; mi < 4; ++mi) {
#pragma unroll
        for (int j = 0; j < 4; ++j) {
            const size_t row = (size_t)(r0 + mi * 16 + j);
            float* op = Out + (row * NMASK + m) * OUT_D + c0;
#pragma unroll
            for (int ni = 0; ni < 2; ++ni)
                op[ni * 16] = acc[mi][ni][j];
        }
    }
}

// ================= fallback (r9 fused kernel, ws too small) =================
#define FAKP 40
#define FBKP 34
#define FMFSZ (32 * BN)

__global__ void __launch_bounds__(THREADS, 4)
mdl_fused_fallback(const float* __restrict__ X,
                   const float* __restrict__ Kn,
                   const float* __restrict__ Mk,
                   float* __restrict__ Out)
{
    __shared__ __align__(16) float          Mf[3 * FMFSZ];
    __shared__ __align__(16) unsigned short As[BM * FAKP];
    __shared__ __align__(16) unsigned short Bs[BN * FBKP];

    const int t = threadIdx.x;
    const int l = t & 63;
    const int w = t >> 6;

    const int raw = blockIdx.x;
    const int wg  = (raw & 7) * 64 + (raw >> 3);
    const int m   = wg >> 5;
    const int ob  = (wg >> 2) & 7;
    const int bb  = wg & 3;

    const int wr = w >> 2, wc = w & 3;

    f32x4 acc[4][2];
#pragma unroll
    for (int mi = 0; mi < 4; ++mi)
#pragma unroll
        for (int ni = 0; ni < 2; ++ni)
            acc[mi][ni] = (f32x4){0.f, 0.f, 0.f, 0.f};

    const int a_row = t >> 2;
    const int a_kh  = (t & 3) * 8;
    const int o2 = (t & 63) * 2;
    const int k4 = w * 4;

    const int obase = ob * BN;
    const float* Xa  = X + ((size_t)(bb * BM + a_row) * NMASK + m) * IN_D + a_kh;
    const float* Knb = Kn + obase + o2;
    const float* Mkm = Mk + (size_t)m * IN_D * OUT_D;

    auto DMA = [&](int tile, int c) {
        const int kt = tile * 32;
#pragma unroll
        for (int j = 0; j < 2; ++j) {
            const int k = j * 16 + w * 2 + (l >> 5);
            const float* gsrc = Mkm + (size_t)(kt + k) * OUT_D + obase + (l & 31) * 4;
            dma16(gsrc, &Mf[c * FMFSZ + j * 2048 + w * 256]);
        }
    };

    DMA(0, 0);
    DMA(1, 1);
    asm volatile("s_waitcnt vmcnt(2)" ::: "memory");
    __builtin_amdgcn_sched_barrier(0);
    __builtin_amdgcn_s_barrier();
    __builtin_amdgcn_sched_barrier(0);

    int c_cur = 0, c_nxt = 1, c_far = 2;

    for (int tt = 0; tt < 32; ++tt) {
        const int kt = tt * 32;
        f32x4 xv0 = *(const f32x4*)(Xa + kt);
        f32x4 xv1 = *(const f32x4*)(Xa + kt + 4);
        f32x2 kv[4];
#pragma unroll
        for (int r = 0; r < 4; ++r)
            kv[r] = *(const f32x2*)(Knb + (size_t)(kt + k4 + r) * OUT_D);
        __builtin_amdgcn_sched_barrier(0);
        DMA((tt + 2 < 32) ? tt + 2 : 0, c_far);
        __builtin_amdgcn_sched_barrier(0);
        {
            f32x2 mvv[4];
#pragma unroll
            for (int r = 0; r < 4; ++r)
                mvv[r] = *(const f32x2*)(&Mf[c_cur * FMFSZ + (k4 + r) * BN + o2]);
#pragma unroll
            for (int c = 0; c < 2; ++c) {
                bf16x4 v;
#pragma unroll
                for (int r = 0; r < 4; ++r)
                    v[r] = (__bf16)(kv[r][c] * mvv[r][c]);
                *(bf16x4*)(&Bs[(o2 + c) * FBKP + k4]) = v;
            }
            bf16x8 va;
#pragma unroll
            for (int j = 0; j < 4; ++j) {
                va[j] = (__bf16)xv0[j]; va[4 + j] = (__bf16)xv1[j];
            }
            *(bf16x8*)(&As[a_row * FAKP + a_kh]) = va;
        }
        asm volatile("s_waitcnt lgkmcnt(0)" ::: "memory");
        __builtin_amdgcn_sched_barrier(0);
        __builtin_amdgcn_s_barrier();
        __builtin_amdgcn_sched_barrier(0);
        {
            const int kg = (l >> 4) * 8;
            bf16x8 bfv[2];
#pragma unroll
            for (int ni = 0; ni < 2; ++ni) {
                const int n = wc * 32 + ni * 16 + (l & 15);
                bf16x4 lo = *(const bf16x4*)(&Bs[n * FBKP + kg]);
                bf16x4 hi = *(const bf16x4*)(&Bs[n * FBKP + kg + 4]);
                bf16x8 f;
                f[0] = lo[0]; f[1] = lo[1]; f[2] = lo[2]; f[3] = lo[3];
                f[4] = hi[0]; f[5] = hi[1]; f[6] = hi[2]; f[7] = hi[3];
                bfv[ni] = f;
            }
#pragma unroll
            for (int mi = 0; mi < 4; ++mi) {
                const int r = wr * 64 + mi * 16 + (l & 15);
                bf16x8 af = *(const bf16x8*)(&As[r * FAKP + kg]);
#pragma unroll
                for (int ni = 0; ni < 2; ++ni)
                    acc[mi][ni] = __builtin_amdgcn_mfma_f32_16x16x32_bf16(
                        af, bfv[ni], acc[mi][ni], 0, 0, 0);
            }
        }
        asm volatile("s_waitcnt vmcnt(2)" ::: "memory");
        __builtin_amdgcn_sched_barrier(0);
        __builtin_amdgcn_s_barrier();
        __builtin_amdgcn_sched_barrier(0);
        const int tmp = c_cur; c_cur = c_nxt; c_nxt = c_far; c_far = tmp;
    }
    asm volatile("s_waitcnt vmcnt(0)" ::: "memory");

    const int r0 = bb * BM + wr * 64 + (l >> 4) * 4;
    const int c0 = ob * BN + wc * 32 + (l & 15);
#pragma unroll
    for (int mi = 0; mi < 4; ++mi) {
#pragma unroll
        for (int j = 0; j < 4; ++j) {
            const size_t row = (size_t)(r0 + mi * 16 + j);
            float* op = Out + (row * NMASK + m) * OUT_D + c0;
#pragma unroll
            for (int ni = 0; ni < 2; ++ni)
                op[ni * 16] = acc[mi][ni][j];
        }
    }
}

extern "C" void kernel_launch(void* const* d_in, const int* in_sizes, int n_in,
                              void* d_out, int out_size, void* d_ws, size_t ws_size,
                              hipStream_t stream) {
    (void)in_sizes; (void)n_in; (void)out_size;
    const float* X  = (const float*)d_in[0];
    const float* Kn = (const float*)d_in[1];
    const float* Mk = (const float*)d_in[2];
    float* Out = (float*)d_out;

    if (ws_size >= (size_t)NMASK * IN_D * OUT_D * sizeof(unsigned short)) {  // 32 MiB
        unsigned short* Wt = (unsigned short*)d_ws;
        mdl_prep_w<<<NMASK * 8 * NT, THREADS, 0, stream>>>(Kn, Mk, Wt);      // 2048
        mdl_gemm<<<(BATCH / BM) * (OUT_D / BN) * NMASK, THREADS, 0, stream>>>(X, Wt, Out);
    } else {
        mdl_fused_fallback<<<512, THREADS, 0, stream>>>(X, Kn, Mk, Out);
    }
}